// Round 1
// baseline (433.092 us; speedup 1.0000x reference)
//
#include <hip/hip_runtime.h>
#include <hip/hip_bf16.h>

#define IN_CH 128
#define OUT_CH 64

// ---------------- degree count ----------------
__global__ void count_kernel(const int* __restrict__ col, int* __restrict__ cnt, int E) {
    int e = blockIdx.x * blockDim.x + threadIdx.x;
    if (e < E) atomicAdd(&cnt[col[e]], 1);
}

// ---------------- exclusive scan (single block) + dis = rsqrt(deg+1) ----------------
__global__ void __launch_bounds__(1024) scan_kernel(const int* __restrict__ cnt,
                                                    int* __restrict__ off,
                                                    int* __restrict__ pos,
                                                    float* __restrict__ dis, int n) {
    const int T = 1024;
    __shared__ int ps[T];
    int tid = threadIdx.x;
    int chunk = (n + T - 1) / T;
    int start = tid * chunk;
    int end = min(start + chunk, n);
    int s = 0;
    for (int i = start; i < end; ++i) s += cnt[i];
    ps[tid] = s;
    __syncthreads();
    for (int d = 1; d < T; d <<= 1) {
        int v = 0;
        if (tid >= d) v = ps[tid - d];
        __syncthreads();
        if (tid >= d) ps[tid] += v;
        __syncthreads();
    }
    int run = (tid == 0) ? 0 : ps[tid - 1];
    for (int i = start; i < end; ++i) {
        int c = cnt[i];
        off[i] = run;
        pos[i] = run;
        dis[i] = rsqrtf((float)(c + 1));   // +1 self-loop, matches gcn_norm
        run += c;
    }
    if (tid == T - 1) off[n] = run;
}

// ---------------- scatter edges into CSR order, pack (row, norm) ----------------
__global__ void scatter_kernel(const int* __restrict__ row, const int* __restrict__ col,
                               const float* __restrict__ dis, int* __restrict__ pos,
                               int2* __restrict__ edges, int E) {
    int e = blockIdx.x * blockDim.x + threadIdx.x;
    if (e < E) {
        int r = row[e], c = col[e];
        int p = atomicAdd(&pos[c], 1);
        float nrm = dis[r] * dis[c];
        edges[p] = make_int2(r, __float_as_int(nrm));
    }
}

// ---------------- Y = X @ W^T  (fp32, W^T staged in LDS) ----------------
__global__ void __launch_bounds__(256) gemm_kernel(const float* __restrict__ x,
                                                   const float* __restrict__ W,
                                                   float* __restrict__ y, int n) {
    __shared__ float Wt[IN_CH * OUT_CH];   // 32 KB, Wt[k*64+o] = W[o*128+k]
    for (int idx = threadIdx.x; idx < IN_CH * OUT_CH; idx += 256) {
        int k = idx >> 6, o = idx & 63;
        Wt[idx] = W[o * IN_CH + k];
    }
    __syncthreads();
    int lane = threadIdx.x & 63;
    int wid = threadIdx.x >> 6;
    int nPairs = n >> 1;   // n is even (50000)
    for (int p = blockIdx.x * 4 + wid; p < nPairs; p += gridDim.x * 4) {
        int v0 = 2 * p, v1 = 2 * p + 1;
        const float4* x0 = (const float4*)(x + (size_t)v0 * IN_CH);
        const float4* x1 = (const float4*)(x + (size_t)v1 * IN_CH);
        float acc0 = 0.f, acc1 = 0.f;
#pragma unroll
        for (int k4 = 0; k4 < IN_CH / 4; ++k4) {
            float4 a = x0[k4];
            float4 bq = x1[k4];
            int k = k4 * 4;
            float w0 = Wt[(k + 0) * 64 + lane];
            float w1 = Wt[(k + 1) * 64 + lane];
            float w2 = Wt[(k + 2) * 64 + lane];
            float w3 = Wt[(k + 3) * 64 + lane];
            acc0 += a.x * w0 + a.y * w1 + a.z * w2 + a.w * w3;
            acc1 += bq.x * w0 + bq.y * w1 + bq.z * w2 + bq.w * w3;
        }
        y[(size_t)v0 * OUT_CH + lane] = acc0;
        y[(size_t)v1 * OUT_CH + lane] = acc1;
    }
}

// ---------------- one propagation hop: wave per node, lane = feature ----------------
template <bool FINAL>
__global__ void __launch_bounds__(256) hop_kernel(const float* __restrict__ yin,
                                                  float* __restrict__ yout,
                                                  const int2* __restrict__ edges,
                                                  const int* __restrict__ off,
                                                  const float* __restrict__ dis,
                                                  const float* __restrict__ bias, int n) {
    int wid = (blockIdx.x * 256 + threadIdx.x) >> 6;
    int lane = threadIdx.x & 63;
    if (wid >= n) return;
    int v = wid;
    int s = off[v], e = off[v + 1];
    float dv = dis[v];
    float acc = dv * dv * yin[(size_t)v * OUT_CH + lane];   // self-loop term
    int i = s;
    for (; i + 4 <= e; i += 4) {
        int2 e0 = edges[i], e1 = edges[i + 1], e2 = edges[i + 2], e3 = edges[i + 3];
        float y0 = yin[(size_t)e0.x * OUT_CH + lane];
        float y1 = yin[(size_t)e1.x * OUT_CH + lane];
        float y2 = yin[(size_t)e2.x * OUT_CH + lane];
        float y3 = yin[(size_t)e3.x * OUT_CH + lane];
        acc += __int_as_float(e0.y) * y0;
        acc += __int_as_float(e1.y) * y1;
        acc += __int_as_float(e2.y) * y2;
        acc += __int_as_float(e3.y) * y3;
    }
    for (; i < e; ++i) {
        int2 ed = edges[i];
        acc += __int_as_float(ed.y) * yin[(size_t)ed.x * OUT_CH + lane];
    }
    if (FINAL) acc += bias[lane];
    yout[(size_t)v * OUT_CH + lane] = acc;
}

extern "C" void kernel_launch(void* const* d_in, const int* in_sizes, int n_in,
                              void* d_out, int out_size, void* d_ws, size_t ws_size,
                              hipStream_t stream) {
    const float* x = (const float*)d_in[0];
    const int* ei = (const int*)d_in[1];
    const float* W = (const float*)d_in[2];
    const float* b = (const float*)d_in[3];
    int n = in_sizes[0] / IN_CH;   // 50000
    int E = in_sizes[1] / 2;       // 800000
    const int* row = ei;           // edge_index[0] = source
    const int* col = ei + E;       // edge_index[1] = target

    char* ws = (char*)d_ws;
    size_t o = 0;
    auto alloc = [&](size_t bytes) -> void* {
        void* p = ws + o;
        o += (bytes + 255) & ~(size_t)255;
        return p;
    };
    int*   cnt   = (int*)alloc((size_t)n * 4);
    int*   off   = (int*)alloc((size_t)(n + 1) * 4);
    int*   pos   = (int*)alloc((size_t)n * 4);
    float* dis   = (float*)alloc((size_t)n * 4);
    int2*  edges = (int2*)alloc((size_t)E * 8);
    float* yA    = (float*)alloc((size_t)n * OUT_CH * 4);
    float* yB    = (float*)alloc((size_t)n * OUT_CH * 4);

    hipMemsetAsync(cnt, 0, (size_t)n * 4, stream);
    count_kernel<<<(E + 255) / 256, 256, 0, stream>>>(col, cnt, E);
    scan_kernel<<<1, 1024, 0, stream>>>(cnt, off, pos, dis, n);
    scatter_kernel<<<(E + 255) / 256, 256, 0, stream>>>(row, col, dis, pos, edges, E);
    gemm_kernel<<<1024, 256, 0, stream>>>(x, W, yA, n);
    int hopBlocks = (n + 3) / 4;   // 4 waves (nodes) per 256-thread block
    hop_kernel<false><<<hopBlocks, 256, 0, stream>>>(yA, yB, edges, off, dis, nullptr, n);
    hop_kernel<true><<<hopBlocks, 256, 0, stream>>>(yB, (float*)d_out, edges, off, dis, b, n);
}

// Round 2
// 305.299 us; speedup vs baseline: 1.4186x; 1.4186x over previous
//
#include <hip/hip_runtime.h>
#include <hip/hip_bf16.h>

#define IN_CH 128
#define OUT_CH 64

// ---------------- degree count ----------------
__global__ void count_kernel(const int* __restrict__ col, int* __restrict__ cnt, int E) {
    int e = blockIdx.x * blockDim.x + threadIdx.x;
    if (e < E) atomicAdd(&cnt[col[e]], 1);
}

// ---------------- 3-phase parallel exclusive scan ----------------
// Phase A: per-tile (256 elems) sums
__global__ void __launch_bounds__(256) partial_kernel(const int* __restrict__ cnt,
                                                      int* __restrict__ bsum, int n) {
    __shared__ int red[256];
    int tid = threadIdx.x;
    int i = blockIdx.x * 256 + tid;
    red[tid] = (i < n) ? cnt[i] : 0;
    __syncthreads();
    for (int d = 128; d > 0; d >>= 1) {
        if (tid < d) red[tid] += red[tid + d];
        __syncthreads();
    }
    if (tid == 0) bsum[blockIdx.x] = red[0];
}

// Phase B: exclusive scan of tile sums (nb <= 256)
__global__ void __launch_bounds__(256) scansums_kernel(int* __restrict__ bsum, int nb) {
    __shared__ int ps[256];
    int tid = threadIdx.x;
    int v = (tid < nb) ? bsum[tid] : 0;
    ps[tid] = v;
    __syncthreads();
    for (int d = 1; d < 256; d <<= 1) {
        int t = 0;
        if (tid >= d) t = ps[tid - d];
        __syncthreads();
        if (tid >= d) ps[tid] += t;
        __syncthreads();
    }
    if (tid < nb) bsum[tid] = ps[tid] - v;   // exclusive
}

// Phase C: per-tile scan + base -> off/pos/dis
__global__ void __launch_bounds__(256) scanwrite_kernel(const int* __restrict__ cnt,
                                                        const int* __restrict__ bsum,
                                                        int* __restrict__ off,
                                                        int* __restrict__ pos,
                                                        float* __restrict__ dis, int n) {
    __shared__ int ps[256];
    int tid = threadIdx.x;
    int i = blockIdx.x * 256 + tid;
    int c = (i < n) ? cnt[i] : 0;
    ps[tid] = c;
    __syncthreads();
    for (int d = 1; d < 256; d <<= 1) {
        int t = 0;
        if (tid >= d) t = ps[tid - d];
        __syncthreads();
        if (tid >= d) ps[tid] += t;
        __syncthreads();
    }
    int excl = ps[tid] - c + bsum[blockIdx.x];
    if (i < n) {
        off[i] = excl;
        pos[i] = excl;
        dis[i] = rsqrtf((float)(c + 1));   // +1 self-loop, matches gcn_norm
        if (i == n - 1) off[n] = excl + c;
    }
}

// ---------------- scatter edges into CSR order, pack (row, norm) ----------------
__global__ void scatter_kernel(const int* __restrict__ row, const int* __restrict__ col,
                               const float* __restrict__ dis, int* __restrict__ pos,
                               int2* __restrict__ edges, int E) {
    int e = blockIdx.x * blockDim.x + threadIdx.x;
    if (e < E) {
        int r = row[e], c = col[e];
        int p = atomicAdd(&pos[c], 1);
        float nrm = dis[r] * dis[c];
        edges[p] = make_int2(r, __float_as_int(nrm));
    }
}

// ---------------- Y = X @ W^T  (fp32, W^T staged in LDS) ----------------
__global__ void __launch_bounds__(256) gemm_kernel(const float* __restrict__ x,
                                                   const float* __restrict__ W,
                                                   float* __restrict__ y, int n) {
    __shared__ float Wt[IN_CH * OUT_CH];   // 32 KB, Wt[k*64+o] = W[o*128+k]
    for (int idx = threadIdx.x; idx < IN_CH * OUT_CH; idx += 256) {
        int k = idx >> 6, o = idx & 63;
        Wt[idx] = W[o * IN_CH + k];
    }
    __syncthreads();
    int lane = threadIdx.x & 63;
    int wid = threadIdx.x >> 6;
    int nPairs = n >> 1;   // n is even (50000)
    for (int p = blockIdx.x * 4 + wid; p < nPairs; p += gridDim.x * 4) {
        int v0 = 2 * p, v1 = 2 * p + 1;
        const float4* x0 = (const float4*)(x + (size_t)v0 * IN_CH);
        const float4* x1 = (const float4*)(x + (size_t)v1 * IN_CH);
        float acc0 = 0.f, acc1 = 0.f;
#pragma unroll
        for (int k4 = 0; k4 < IN_CH / 4; ++k4) {
            float4 a = x0[k4];
            float4 bq = x1[k4];
            int k = k4 * 4;
            float w0 = Wt[(k + 0) * 64 + lane];
            float w1 = Wt[(k + 1) * 64 + lane];
            float w2 = Wt[(k + 2) * 64 + lane];
            float w3 = Wt[(k + 3) * 64 + lane];
            acc0 += a.x * w0 + a.y * w1 + a.z * w2 + a.w * w3;
            acc1 += bq.x * w0 + bq.y * w1 + bq.z * w2 + bq.w * w3;
        }
        y[(size_t)v0 * OUT_CH + lane] = acc0;
        y[(size_t)v1 * OUT_CH + lane] = acc1;
    }
}

// ---------------- one propagation hop: wave per node, lane = feature ----------------
template <bool FINAL>
__global__ void __launch_bounds__(256) hop_kernel(const float* __restrict__ yin,
                                                  float* __restrict__ yout,
                                                  const int2* __restrict__ edges,
                                                  const int* __restrict__ off,
                                                  const float* __restrict__ dis,
                                                  const float* __restrict__ bias, int n) {
    int wid = (blockIdx.x * 256 + threadIdx.x) >> 6;
    int lane = threadIdx.x & 63;
    if (wid >= n) return;
    int v = wid;
    int s = off[v], e = off[v + 1];
    float dv = dis[v];
    float acc = dv * dv * yin[(size_t)v * OUT_CH + lane];   // self-loop term
    int i = s;
    for (; i + 4 <= e; i += 4) {
        int2 e0 = edges[i], e1 = edges[i + 1], e2 = edges[i + 2], e3 = edges[i + 3];
        float y0 = yin[(size_t)e0.x * OUT_CH + lane];
        float y1 = yin[(size_t)e1.x * OUT_CH + lane];
        float y2 = yin[(size_t)e2.x * OUT_CH + lane];
        float y3 = yin[(size_t)e3.x * OUT_CH + lane];
        acc += __int_as_float(e0.y) * y0;
        acc += __int_as_float(e1.y) * y1;
        acc += __int_as_float(e2.y) * y2;
        acc += __int_as_float(e3.y) * y3;
    }
    for (; i < e; ++i) {
        int2 ed = edges[i];
        acc += __int_as_float(ed.y) * yin[(size_t)ed.x * OUT_CH + lane];
    }
    if (FINAL) acc += bias[lane];
    yout[(size_t)v * OUT_CH + lane] = acc;
}

extern "C" void kernel_launch(void* const* d_in, const int* in_sizes, int n_in,
                              void* d_out, int out_size, void* d_ws, size_t ws_size,
                              hipStream_t stream) {
    const float* x = (const float*)d_in[0];
    const int* ei = (const int*)d_in[1];
    const float* W = (const float*)d_in[2];
    const float* b = (const float*)d_in[3];
    int n = in_sizes[0] / IN_CH;   // 50000
    int E = in_sizes[1] / 2;       // 800000
    const int* row = ei;           // edge_index[0] = source
    const int* col = ei + E;       // edge_index[1] = target

    char* ws = (char*)d_ws;
    size_t o = 0;
    auto alloc = [&](size_t bytes) -> void* {
        void* p = ws + o;
        o += (bytes + 255) & ~(size_t)255;
        return p;
    };
    int*   cnt   = (int*)alloc((size_t)n * 4);
    int*   off   = (int*)alloc((size_t)(n + 1) * 4);
    int*   pos   = (int*)alloc((size_t)n * 4);
    float* dis   = (float*)alloc((size_t)n * 4);
    int2*  edges = (int2*)alloc((size_t)E * 8);
    float* yA    = (float*)alloc((size_t)n * OUT_CH * 4);
    float* yB    = (float*)alloc((size_t)n * OUT_CH * 4);
    int*   bsum  = (int*)alloc(1024 * 4);

    int nTiles = (n + 255) / 256;  // 196

    hipMemsetAsync(cnt, 0, (size_t)n * 4, stream);
    count_kernel<<<(E + 255) / 256, 256, 0, stream>>>(col, cnt, E);
    partial_kernel<<<nTiles, 256, 0, stream>>>(cnt, bsum, n);
    scansums_kernel<<<1, 256, 0, stream>>>(bsum, nTiles);
    scanwrite_kernel<<<nTiles, 256, 0, stream>>>(cnt, bsum, off, pos, dis, n);
    scatter_kernel<<<(E + 255) / 256, 256, 0, stream>>>(row, col, dis, pos, edges, E);
    gemm_kernel<<<1024, 256, 0, stream>>>(x, W, yA, n);
    int hopBlocks = (n + 3) / 4;   // 4 waves (nodes) per 256-thread block
    hop_kernel<false><<<hopBlocks, 256, 0, stream>>>(yA, yB, edges, off, dis, nullptr, n);
    hop_kernel<true><<<hopBlocks, 256, 0, stream>>>(yB, (float*)d_out, edges, off, dis, b, n);
}